// Round 11
// baseline (218.941 us; speedup 1.0000x reference)
//
#include <hip/hip_runtime.h>
#include <stdint.h>

#define LOG2E 1.4426950408889634f
#define QSCALE 0.18033688011112042f  // 0.125 * log2(e), folded into Q at GEMM1

typedef __attribute__((ext_vector_type(8))) short bf16x8;
typedef __attribute__((ext_vector_type(4))) float f32x4;
typedef __attribute__((ext_vector_type(8))) unsigned short u16x8;

#define B_ 2
#define T_ 2048
#define C_ 1024
#define H_ 16
#define D_ 64
#define BT_ 4096
#define N3_ 3072

#if __has_builtin(__builtin_amdgcn_exp2f)
#define EXP2(x) __builtin_amdgcn_exp2f(x)   // raw v_exp_f32 (inputs bounded, no denorm path)
#else
#define EXP2(x) exp2f(x)
#endif

__device__ __forceinline__ unsigned short f2bf(float f) {
  union { float f; unsigned u; } x; x.f = f;
  return (unsigned short)((x.u + 0x7fffu + ((x.u >> 16) & 1u)) >> 16);
}
__device__ __forceinline__ float bf2f(unsigned short u) {
  union { unsigned u; float f; } x; x.u = ((unsigned)u) << 16;
  return x.f;
}
__device__ __forceinline__ unsigned f2u(float f) {
  union { float f; unsigned u; } x; x.f = f; return x.u;
}
// pack two f32 -> dword of 2 bf16 (low short = a, high = b), round-nearest-away
__device__ __forceinline__ unsigned pack_bf2(float a, float b) {
  return __builtin_amdgcn_perm(f2u(b) + 0x8000u, f2u(a) + 0x8000u, 0x07060302u);
}

// async global->LDS 16B (m97 pattern). LDS dest must be wave-uniform base +
// lane*16 — all call sites below keep lds addr == linear(slot)*16B.
__device__ __forceinline__ void gld16(const unsigned short* g, unsigned short* l) {
  __builtin_amdgcn_global_load_lds(
      (const __attribute__((address_space(1))) unsigned int*)g,
      (__attribute__((address_space(3))) unsigned int*)l, 16, 0, 0);
}

// ---------------- prep (merged r11): cvt + 2 transposes in one launch ---------
// block 256. bid [0,4096): x fp32->bf16. [4096,7168): w_qkv tr. [7168,8192): w_proj tr.
__device__ __forceinline__ void tr32(const float* __restrict__ in,
                                     unsigned short* __restrict__ out,
                                     int K, int N, int b, int nbx, int tid) {
  __shared__ unsigned short tile[32][33];
  const int bx = b % nbx, by = b / nbx;
  const int n0 = bx * 32, k0 = by * 32;
  const int tx = tid & 31, ty = (tid >> 5) * 4;
#pragma unroll
  for (int r = 0; r < 4; r++)
    tile[ty + r][tx] = f2bf(in[(size_t)(k0 + ty + r) * N + n0 + tx]);
  __syncthreads();
#pragma unroll
  for (int r = 0; r < 4; r++)
    out[(size_t)(n0 + ty + r) * K + k0 + tx] = tile[tx][ty + r];
}

__global__ __launch_bounds__(256) void prep_kernel(
    const float* __restrict__ x, unsigned short* __restrict__ xb,
    const float* __restrict__ wq, unsigned short* __restrict__ wqT,
    const float* __restrict__ wp, unsigned short* __restrict__ wpT) {
  const int bid = blockIdx.x, tid = threadIdx.x;
  if (bid < 4096) {
    int i = (bid * 256 + tid) * 4;
    float4 v = *(const float4*)(x + i);
    ushort4 o;
    o.x = f2bf(v.x); o.y = f2bf(v.y); o.z = f2bf(v.z); o.w = f2bf(v.w);
    *(ushort4*)(xb + i) = o;
  } else if (bid < 4096 + 3072) {
    tr32(wq, wqT, 1024, 3072, bid - 4096, 96, tid);
  } else {
    tr32(wp, wpT, 1024, 1024, bid - 7168, 32, tid);
  }
}

// ---------------- GEMM: C[m][n] = sum_k A[m][k] * Bt[n][k], K=1024 ----------------
// r11 restructured K-loop: A via global_load_lds (swizzled LDS, shared by all
// waves), B DIRECT global->VGPR (AITER-style). r10 arithmetic: 12 ds_read_b128
// per wave-iter = ~47% of runtime on the LDS pipe — B-from-registers cuts
// ds_reads to 8 and gld16 to 4, and the B loads are issued before the
// vmcnt-drain barrier so their latency hides under the A-staging drain.
// 128x64 tile, BK=64, 16 iters, LDS 16KB.
// MODE 0: scatter-write q*QSCALE [B,H,T,D], k [B,H,T,D], v [B,H,D,T] bf16
// MODE 1: write fp32 out [m][n] (N=1024)
template <int MODE>
__global__ __launch_bounds__(256) void gemm_kernel(
    const unsigned short* __restrict__ A, const unsigned short* __restrict__ Bt,
    unsigned short* __restrict__ qo, unsigned short* __restrict__ ko,
    unsigned short* __restrict__ vo, float* __restrict__ fo) {
  __shared__ unsigned short As[128 * 64];   // [row][64], chunk-swizzled
  const int tid = threadIdx.x;
  const int wave = tid >> 6, lane = tid & 63;
  const int quad = lane >> 4, l16 = lane & 15;
  const int wm = (wave >> 1) * 64, wn = (wave & 1) * 32;
  const int m0 = blockIdx.y * 128, n0 = blockIdx.x * 64;

  f32x4 acc[4][2] = {};

  // B-operand fragment pointers: n = n0+wn+ni*16+l16 (row), k-offset quad*8
  const unsigned short* Bp0 = Bt + (size_t)(n0 + wn + l16) * 1024 + quad * 8;
  const unsigned short* Bp1 = Bp0 + 16 * 1024;

  for (int k = 0; k < 1024; k += 64) {
    __syncthreads();
    // A: 1024 slots (4/thread). slot s: row=s>>3, ch=s&7;
    // global col = k + (ch^(row&7))*8; lds = s*16B (lane-linear)
#pragma unroll
    for (int i = 0; i < 4; i++) {
      const int s = tid + 256 * i;
      const int row = s >> 3, ch = s & 7;
      gld16(A + (size_t)(m0 + row) * 1024 + k + ((ch ^ (row & 7)) * 8), As + s * 8);
    }
    // B fragments for this iter: issued before the drain barrier -> latency
    // overlaps the gld16 drain. [sub][ni]
    bf16x8 b00 = *(const bf16x8*)(Bp0 + k);
    bf16x8 b01 = *(const bf16x8*)(Bp1 + k);
    bf16x8 b10 = *(const bf16x8*)(Bp0 + k + 32);
    bf16x8 b11 = *(const bf16x8*)(Bp1 + k + 32);
    __syncthreads();
#pragma unroll
    for (int sub = 0; sub < 2; sub++) {
      bf16x8 af[4];
#pragma unroll
      for (int mi = 0; mi < 4; mi++) {
        const int row = wm + mi * 16 + l16;
        af[mi] = *(const bf16x8*)(As + row * 64 + (((sub * 4 + quad) ^ (row & 7)) * 8));
      }
      const bf16x8 bz0 = sub ? b10 : b00;
      const bf16x8 bz1 = sub ? b11 : b01;
#pragma unroll
      for (int mi = 0; mi < 4; mi++) {
        acc[mi][0] = __builtin_amdgcn_mfma_f32_16x16x32_bf16(af[mi], bz0, acc[mi][0], 0, 0, 0);
        acc[mi][1] = __builtin_amdgcn_mfma_f32_16x16x32_bf16(af[mi], bz1, acc[mi][1], 0, 0, 0);
      }
    }
  }

  // epilogue: C/D layout col=l16, row=quad*4+r (m89/m91-verified)
  if (MODE == 0) {
    const int part = n0 >> 10;          // block-uniform
    const int hh = (n0 >> 6) & 15;      // block-uniform
#pragma unroll
    for (int mi = 0; mi < 4; mi++) {
#pragma unroll
      for (int r = 0; r < 4; r++) {
        const int m = m0 + wm + mi * 16 + quad * 4 + r;
        const int b = m >> 11, t = m & 2047;
#pragma unroll
        for (int ni = 0; ni < 2; ni++) {
          const int d = wn + ni * 16 + l16;
          float val = acc[mi][ni][r];
          if (part == 0) val *= QSCALE;   // fold softmax scale into Q (fp32, free)
          const unsigned short bv = f2bf(val);
          if (part == 0)
            qo[((size_t)(b * H_ + hh) * T_ + t) * D_ + d] = bv;
          else if (part == 1)
            ko[((size_t)(b * H_ + hh) * T_ + t) * D_ + d] = bv;
          else
            vo[((size_t)(b * H_ + hh) * D_ + d) * T_ + t] = bv;  // V pre-transposed [B,H,D,T]
        }
      }
    }
  } else {
#pragma unroll
    for (int mi = 0; mi < 4; mi++)
#pragma unroll
      for (int r = 0; r < 4; r++) {
        const int m = m0 + wm + mi * 16 + quad * 4 + r;
#pragma unroll
        for (int ni = 0; ni < 2; ni++)
          fo[(size_t)m * 1024 + n0 + wn + ni * 16 + l16] = acc[mi][ni][r];
      }
  }
}

// ---------------- flash attention: block staging + split-K + S^T softmax ------
// (r10 config: XCD-local bh = bid&31, longest chunks first — unchanged)
__global__ __launch_bounds__(256) void attn_kernel(
    const unsigned short* __restrict__ qb, const unsigned short* __restrict__ kb,
    const unsigned short* __restrict__ vb, unsigned short* __restrict__ yb,
    unsigned short* __restrict__ po, float* __restrict__ pl) {
  const int tid = threadIdx.x;
  const int wave = tid >> 6, lane = tid & 63;
  const int quad = lane >> 4, l16 = lane & 15;

  const int bid = blockIdx.x;
  const int bh = bid & 31;          // XCD-local: all 63 blocks of bh on one XCD
  const int u = 62 - (bid >> 5);    // longest chunks first
  int qs, c, nch;
  if (u < 11) { qs = u; c = 0; nch = 1; }
  else if (u < 33) { int v = u - 11; qs = 11 + (v >> 1); c = v & 1; nch = 2; }
  else { int v = u - 33; qs = 22 + v / 3; c = v % 3; nch = 3; }
  const int nt = qs + 1;
  const int j0 = c * nt / nch, j1 = (c + 1) * nt / nch;
  const int b = bh >> 4, h = bh & 15;

  __shared__ unsigned short Ks[64 * 64];     // [s][d], chunk-swizzled
  __shared__ unsigned short Vt[64 * 64];     // [d][s], chunk-swizzled
  __shared__ unsigned short Ps[4 * 16 * 68]; // per-wave P [q][s], stride 68
  unsigned short* Pw = Ps + wave * 16 * 68;

  const unsigned short* Qg = qb + (size_t)bh * T_ * D_;
  const unsigned short* Kg = kb + (size_t)bh * T_ * D_;
  const unsigned short* Vg = vb + (size_t)bh * D_ * T_;

  // Q fragment (B-operand: n=q=l16, k=d=quad*8+j)
  const unsigned short* qp = Qg + (size_t)(qs * 64 + wave * 16 + l16) * D_ + quad * 8;
  bf16x8 qf0 = *(const bf16x8*)qp, qf1 = *(const bf16x8*)(qp + 32);

  f32x4 o[4] = {};
  float lacc = 0.f;
  const int qglob = qs * 64 + wave * 16 + l16;   // this lane's q (S^T: col=l16)
  const int sloc_base = quad * 4;                // s-local row base (S^T: row=quad*4+r)

  const int trow = tid >> 3, tch = tid & 7;

  for (int jt = j0; jt < j1; jt++) {
    const int s0 = jt * 64;
    __syncthreads();
    {
      const int r0 = trow, r1 = trow + 32;
      gld16(Kg + (size_t)(s0 + r0) * D_ + ((tch ^ (r0 & 7)) * 8), Ks + r0 * 64 + tch * 8);
      gld16(Kg + (size_t)(s0 + r1) * D_ + ((tch ^ (r1 & 7)) * 8), Ks + r1 * 64 + tch * 8);
      gld16(Vg + (size_t)r0 * T_ + s0 + ((tch ^ (r0 & 7)) * 8), Vt + r0 * 64 + tch * 8);
      gld16(Vg + (size_t)r1 * T_ + s0 + ((tch ^ (r1 & 7)) * 8), Vt + r1 * 64 + tch * 8);
    }
    __syncthreads();

    // S^T = K Q^T : K as A-operand, Q as B-operand.
    // C-layout of s[mi]: row = s-local = mi*16+quad*4+r, col = q = l16.
    f32x4 s[4];
#pragma unroll
    for (int mi = 0; mi < 4; mi++) {
      const int row = mi * 16 + l16, sw = row & 7;
      bf16x8 kf0 = *(const bf16x8*)(Ks + row * 64 + ((quad ^ sw) * 8));
      bf16x8 kf1 = *(const bf16x8*)(Ks + row * 64 + (((quad + 4) ^ sw) * 8));
      f32x4 z = {0.f, 0.f, 0.f, 0.f};
      z = __builtin_amdgcn_mfma_f32_16x16x32_bf16(kf0, qf0, z, 0, 0, 0);
      s[mi] = __builtin_amdgcn_mfma_f32_16x16x32_bf16(kf1, qf1, z, 0, 0, 0);
    }

    if (jt == qs) {  // uniform diag branch: mask s > q
#pragma unroll
      for (int mi = 0; mi < 4; mi++)
#pragma unroll
        for (int r = 0; r < 4; r++) {
          float p = EXP2(s[mi][r]);
          p = (s0 + mi * 16 + sloc_base + r > qglob) ? 0.f : p;
          s[mi][r] = p;
          lacc += p;
        }
    } else {
#pragma unroll
      for (int mi = 0; mi < 4; mi++)
#pragma unroll
        for (int r = 0; r < 4; r++) {
          float p = EXP2(s[mi][r]);
          s[mi][r] = p;
          lacc += p;
        }
    }

    // P -> LDS [q=l16][s], packed dwords
#pragma unroll
    for (int mi = 0; mi < 4; mi++) {
      unsigned d0 = pack_bf2(s[mi][0], s[mi][1]);
      unsigned d1 = pack_bf2(s[mi][2], s[mi][3]);
      *(uint2*)(Pw + l16 * 68 + mi * 16 + quad * 4) = make_uint2(d0, d1);
    }

    // O += P V : P as A-operand (m=q=l16, k=s), V^T as B-operand
#pragma unroll
    for (int kk = 0; kk < 2; kk++) {
      bf16x8 pf = *(const bf16x8*)(Pw + l16 * 68 + kk * 32 + quad * 8);
#pragma unroll
      for (int ni = 0; ni < 4; ni++) {
        const int row = ni * 16 + l16, sw = row & 7;
        bf16x8 vf = *(const bf16x8*)(Vt + row * 64 + (((kk * 4 + quad) ^ sw) * 8));
        o[ni] = __builtin_amdgcn_mfma_f32_16x16x32_bf16(pf, vf, o[ni], 0, 0, 0);
      }
    }
  }

  // l: sum across the 4 lanes sharing l16 (quads), then fetch per-row values
  lacc += __shfl_xor(lacc, 16, 64);
  lacc += __shfl_xor(lacc, 32, 64);
  float lr[4];
#pragma unroll
  for (int r = 0; r < 4; r++) lr[r] = __shfl(lacc, quad * 4 + r, 16);  // l for q-row quad*4+r

  if (nch == 1) {
#pragma unroll
    for (int r = 0; r < 4; r++) {
      float inv = 1.0f / lr[r];
      int tq = qs * 64 + wave * 16 + quad * 4 + r;
#pragma unroll
      for (int ni = 0; ni < 4; ni++)
        yb[((size_t)(b * T_ + tq)) * 1024 + h * 64 + ni * 16 + l16] = f2bf(o[ni][r] * inv);
    }
  } else {
    const int slot = 52 * bh + ((qs <= 21) ? ((qs - 11) * 2 + c) : (22 + (qs - 22) * 3 + c));
    unsigned short* pob = po + (size_t)slot * 4096;
#pragma unroll
    for (int r = 0; r < 4; r++) {
      const int row64 = wave * 16 + quad * 4 + r;
#pragma unroll
      for (int ni = 0; ni < 4; ni++)
        pob[row64 * 64 + ni * 16 + l16] = f2bf(o[ni][r]);
      if (l16 == 0) pl[slot * 64 + row64] = lr[r];
    }
  }
}

// ---------------- split-K reduce: rows of strips qs>=11 ----------------
__global__ __launch_bounds__(256) void reduce_kernel(
    const unsigned short* __restrict__ po, const float* __restrict__ pl,
    unsigned short* __restrict__ yb) {
  int idx = blockIdx.x * 256 + threadIdx.x;
  int bh = idx / 21504;          // 1344 rows * 16 colgroups
  int rem = idx - bh * 21504;
  int rr = rem >> 4, cg = rem & 15;
  int qs = 11 + (rr >> 6), row64 = rr & 63;
  int base, nch;
  if (qs <= 21) { base = (qs - 11) * 2; nch = 2; }
  else { base = 22 + (qs - 22) * 3; nch = 3; }
  int b = bh >> 4, h = bh & 15;
  float a0 = 0.f, a1 = 0.f, a2 = 0.f, a3 = 0.f, l = 0.f;
  for (int cc = 0; cc < nch; cc++) {
    int slot = 52 * bh + base + cc;
    const unsigned short* p = po + (size_t)slot * 4096 + row64 * 64 + cg * 4;
    ushort4 uv = *(const ushort4*)p;
    a0 += bf2f(uv.x); a1 += bf2f(uv.y); a2 += bf2f(uv.z); a3 += bf2f(uv.w);
    l += pl[slot * 64 + row64];
  }
  float inv = 1.0f / l;
  int tq = qs * 64 + row64;
  ushort4 w;
  w.x = f2bf(a0 * inv); w.y = f2bf(a1 * inv); w.z = f2bf(a2 * inv); w.w = f2bf(a3 * inv);
  *(ushort4*)(yb + ((size_t)(b * T_ + tq)) * 1024 + h * 64 + cg * 4) = w;
}

// ---------------- launch ----------------
extern "C" void kernel_launch(void* const* d_in, const int* in_sizes, int n_in,
                              void* d_out, int out_size, void* d_ws, size_t ws_size,
                              hipStream_t stream) {
  const float* x = (const float*)d_in[0];       // [B,T,C]
  const float* w_qkv = (const float*)d_in[1];   // [C,3C]
  const float* w_proj = (const float*)d_in[2];  // [C,C]
  float* out = (float*)d_out;                   // [B,T,C] fp32

  // ws layout (shorts). po aliases wqkvT (dead after GEMM1). ~49.7 MB total.
  unsigned short* xb = (unsigned short*)d_ws;                 // 4.19M
  unsigned short* wprojT = xb + (size_t)BT_ * C_;             // 1.05M
  unsigned short* qb = wprojT + (size_t)C_ * C_;              // 4.19M
  unsigned short* kb = qb + (size_t)B_ * H_ * T_ * D_;        // 4.19M
  unsigned short* vb = kb + (size_t)B_ * H_ * T_ * D_;        // 4.19M
  unsigned short* wqkvT = vb + (size_t)B_ * H_ * T_ * D_;     // 3.15M
  unsigned short* po = wqkvT;                                 // 1664 slots * 4096 = 6.82M
  float* pl = (float*)(po + (size_t)1664 * 4096);             // 106K fp32
  unsigned short* yb = xb;  // reuse (x dead after GEMM1)

  prep_kernel<<<dim3(8192), 256, 0, stream>>>(x, xb, w_qkv, wqkvT, w_proj, wprojT);

  gemm_kernel<0><<<dim3(N3_ / 64, BT_ / 128), 256, 0, stream>>>(xb, wqkvT, qb, kb, vb, nullptr);
  attn_kernel<<<dim3(32 * 63), 256, 0, stream>>>(qb, kb, vb, yb, po, pl);
  reduce_kernel<<<dim3(2688), 256, 0, stream>>>(po, pl, yb);
  gemm_kernel<1><<<dim3(C_ / 64, BT_ / 128), 256, 0, stream>>>(yb, wprojT, nullptr, nullptr, nullptr, out);
}

// Round 12
// 183.622 us; speedup vs baseline: 1.1923x; 1.1923x over previous
//
#include <hip/hip_runtime.h>
#include <stdint.h>

#define LOG2E 1.4426950408889634f
#define QSCALE 0.18033688011112042f  // 0.125 * log2(e), folded into Q at GEMM1

typedef __attribute__((ext_vector_type(8))) short bf16x8;
typedef __attribute__((ext_vector_type(4))) float f32x4;
typedef __attribute__((ext_vector_type(8))) unsigned short u16x8;

#define B_ 2
#define T_ 2048
#define C_ 1024
#define H_ 16
#define D_ 64
#define BT_ 4096
#define N3_ 3072

#if __has_builtin(__builtin_amdgcn_exp2f)
#define EXP2(x) __builtin_amdgcn_exp2f(x)   // raw v_exp_f32 (inputs bounded, no denorm path)
#else
#define EXP2(x) exp2f(x)
#endif

__device__ __forceinline__ unsigned short f2bf(float f) {
  union { float f; unsigned u; } x; x.f = f;
  return (unsigned short)((x.u + 0x7fffu + ((x.u >> 16) & 1u)) >> 16);
}
__device__ __forceinline__ float bf2f(unsigned short u) {
  union { unsigned u; float f; } x; x.u = ((unsigned)u) << 16;
  return x.f;
}
__device__ __forceinline__ unsigned f2u(float f) {
  union { float f; unsigned u; } x; x.f = f; return x.u;
}
// pack two f32 -> dword of 2 bf16 (low short = a, high = b), round-nearest-away
__device__ __forceinline__ unsigned pack_bf2(float a, float b) {
  return __builtin_amdgcn_perm(f2u(b) + 0x8000u, f2u(a) + 0x8000u, 0x07060302u);
}

// async global->LDS 16B (m97 pattern). LDS dest must be wave-uniform base +
// lane*16 — all call sites below keep lds addr == linear(slot)*16B.
__device__ __forceinline__ void gld16(const unsigned short* g, unsigned short* l) {
  __builtin_amdgcn_global_load_lds(
      (const __attribute__((address_space(1))) unsigned int*)g,
      (__attribute__((address_space(3))) unsigned int*)l, 16, 0, 0);
}

// ---------------- prep (r11-proven): cvt + 2 transposes in one launch ---------
__device__ __forceinline__ void tr32(const float* __restrict__ in,
                                     unsigned short* __restrict__ out,
                                     int K, int N, int b, int nbx, int tid) {
  __shared__ unsigned short tile[32][33];
  const int bx = b % nbx, by = b / nbx;
  const int n0 = bx * 32, k0 = by * 32;
  const int tx = tid & 31, ty = (tid >> 5) * 4;
#pragma unroll
  for (int r = 0; r < 4; r++)
    tile[ty + r][tx] = f2bf(in[(size_t)(k0 + ty + r) * N + n0 + tx]);
  __syncthreads();
#pragma unroll
  for (int r = 0; r < 4; r++)
    out[(size_t)(n0 + ty + r) * K + k0 + tx] = tile[tx][ty + r];
}

__global__ __launch_bounds__(256) void prep_kernel(
    const float* __restrict__ x, unsigned short* __restrict__ xb,
    const float* __restrict__ wq, unsigned short* __restrict__ wqT,
    const float* __restrict__ wp, unsigned short* __restrict__ wpT) {
  const int bid = blockIdx.x, tid = threadIdx.x;
  if (bid < 4096) {
    int i = (bid * 256 + tid) * 4;
    float4 v = *(const float4*)(x + i);
    ushort4 o;
    o.x = f2bf(v.x); o.y = f2bf(v.y); o.z = f2bf(v.z); o.w = f2bf(v.w);
    *(ushort4*)(xb + i) = o;
  } else if (bid < 4096 + 3072) {
    tr32(wq, wqT, 1024, 3072, bid - 4096, 96, tid);
  } else {
    tr32(wp, wpT, 1024, 1024, bid - 7168, 32, tid);
  }
}

// ---------------- GEMM1 (r10 revert — B through swizzled LDS, BK=64) ----------
// r11's B-direct-from-global regressed 49->76us (scattered per-lane loads =
// latency death, the r5 lesson). This is the r10 known-good body: 528 TF.
// MODE 0: scatter-write q*QSCALE [B,H,T,D], k [B,H,T,D], v [B,H,D,T] bf16
// MODE 1: write fp32 out [m][n] (N=1024)
template <int MODE>
__global__ __launch_bounds__(256) void gemm_kernel(
    const unsigned short* __restrict__ A, const unsigned short* __restrict__ Bt,
    unsigned short* __restrict__ qo, unsigned short* __restrict__ ko,
    unsigned short* __restrict__ vo, float* __restrict__ fo) {
  __shared__ unsigned short As[128 * 64];   // [row][64], chunk-swizzled
  __shared__ unsigned short Bs[64 * 64];    // [row][64], chunk-swizzled
  const int tid = threadIdx.x;
  const int wave = tid >> 6, lane = tid & 63;
  const int quad = lane >> 4, l16 = lane & 15;
  const int wm = (wave >> 1) * 64, wn = (wave & 1) * 32;
  const int m0 = blockIdx.y * 128, n0 = blockIdx.x * 64;

  f32x4 acc[4][2] = {};

  for (int k = 0; k < 1024; k += 64) {
    __syncthreads();
#pragma unroll
    for (int i = 0; i < 4; i++) {
      const int s = tid + 256 * i;
      const int row = s >> 3, ch = s & 7;
      gld16(A + (size_t)(m0 + row) * 1024 + k + ((ch ^ (row & 7)) * 8), As + s * 8);
    }
#pragma unroll
    for (int i = 0; i < 2; i++) {
      const int s = tid + 256 * i;
      const int row = s >> 3, ch = s & 7;
      gld16(Bt + (size_t)(n0 + row) * 1024 + k + ((ch ^ (row & 7)) * 8), Bs + s * 8);
    }
    __syncthreads();
#pragma unroll
    for (int sub = 0; sub < 2; sub++) {
      bf16x8 af[4], bfr[2];
#pragma unroll
      for (int mi = 0; mi < 4; mi++) {
        const int row = wm + mi * 16 + l16;
        af[mi] = *(const bf16x8*)(As + row * 64 + (((sub * 4 + quad) ^ (row & 7)) * 8));
      }
#pragma unroll
      for (int ni = 0; ni < 2; ni++) {
        const int row = wn + ni * 16 + l16;
        bfr[ni] = *(const bf16x8*)(Bs + row * 64 + (((sub * 4 + quad) ^ (row & 7)) * 8));
      }
#pragma unroll
      for (int mi = 0; mi < 4; mi++)
#pragma unroll
        for (int ni = 0; ni < 2; ni++)
          acc[mi][ni] = __builtin_amdgcn_mfma_f32_16x16x32_bf16(af[mi], bfr[ni], acc[mi][ni], 0, 0, 0);
    }
  }

  // epilogue: C/D layout col=l16, row=quad*4+r (m89/m91-verified)
  if (MODE == 0) {
    const int part = n0 >> 10;          // block-uniform
    const int hh = (n0 >> 6) & 15;      // block-uniform
#pragma unroll
    for (int mi = 0; mi < 4; mi++) {
#pragma unroll
      for (int r = 0; r < 4; r++) {
        const int m = m0 + wm + mi * 16 + quad * 4 + r;
        const int b = m >> 11, t = m & 2047;
#pragma unroll
        for (int ni = 0; ni < 2; ni++) {
          const int d = wn + ni * 16 + l16;
          float val = acc[mi][ni][r];
          if (part == 0) val *= QSCALE;   // fold softmax scale into Q (fp32, free)
          const unsigned short bv = f2bf(val);
          if (part == 0)
            qo[((size_t)(b * H_ + hh) * T_ + t) * D_ + d] = bv;
          else if (part == 1)
            ko[((size_t)(b * H_ + hh) * T_ + t) * D_ + d] = bv;
          else
            vo[((size_t)(b * H_ + hh) * D_ + d) * T_ + t] = bv;  // V pre-transposed [B,H,D,T]
        }
      }
    }
  } else {
#pragma unroll
    for (int mi = 0; mi < 4; mi++)
#pragma unroll
      for (int r = 0; r < 4; r++) {
        const int m = m0 + wm + mi * 16 + quad * 4 + r;
#pragma unroll
        for (int ni = 0; ni < 2; ni++)
          fo[(size_t)m * 1024 + n0 + wn + ni * 16 + l16] = acc[mi][ni][r];
      }
  }
}

// ---------------- GEMM2: 512-thr split-K-in-block (r12) ----------------------
// r10/r11 data: per-block latency ~48us regardless of 2 or 6 blocks/CU ->
// blocks overlap freely; gemm2 (512 blocks = 2/CU) wastes the machine.
// Split K inside the block: wave-group g in {0,1} computes K in [g*512,g*512+512)
// into its own LDS tiles (8 drain-rounds instead of 16 -> ~half block latency),
// fp32 combine through LDS at the end. Tile 128x64, grid (16,32) unchanged.
__global__ __launch_bounds__(512) void gemm2_kernel(
    const unsigned short* __restrict__ A, const unsigned short* __restrict__ Bt,
    float* __restrict__ fo) {
  __shared__ unsigned short As[2][128 * 64];  // 2 x 16KB, chunk-swizzled
  __shared__ unsigned short Bs[2][64 * 64];   // 2 x 8KB, chunk-swizzled
  const int tid = threadIdx.x;
  const int wave = tid >> 6, lane = tid & 63;
  const int quad = lane >> 4, l16 = lane & 15;
  const int grp = wave >> 2, w4 = wave & 3;
  const int wm = (w4 >> 1) * 64, wn = (w4 & 1) * 32;
  const int m0 = blockIdx.y * 128, n0 = blockIdx.x * 64;
  const int gtid = tid & 255;   // group-local thread id

  f32x4 acc[4][2] = {};
  const int kbase = grp * 512;
  unsigned short* Asg = &As[grp][0];
  unsigned short* Bsg = &Bs[grp][0];

  for (int kk = 0; kk < 512; kk += 64) {
    const int k = kbase + kk;
    __syncthreads();
#pragma unroll
    for (int i = 0; i < 4; i++) {
      const int s = gtid + 256 * i;
      const int row = s >> 3, ch = s & 7;
      gld16(A + (size_t)(m0 + row) * 1024 + k + ((ch ^ (row & 7)) * 8), Asg + s * 8);
    }
#pragma unroll
    for (int i = 0; i < 2; i++) {
      const int s = gtid + 256 * i;
      const int row = s >> 3, ch = s & 7;
      gld16(Bt + (size_t)(n0 + row) * 1024 + k + ((ch ^ (row & 7)) * 8), Bsg + s * 8);
    }
    __syncthreads();
#pragma unroll
    for (int sub = 0; sub < 2; sub++) {
      bf16x8 af[4], bfr[2];
#pragma unroll
      for (int mi = 0; mi < 4; mi++) {
        const int row = wm + mi * 16 + l16;
        af[mi] = *(const bf16x8*)(Asg + row * 64 + (((sub * 4 + quad) ^ (row & 7)) * 8));
      }
#pragma unroll
      for (int ni = 0; ni < 2; ni++) {
        const int row = wn + ni * 16 + l16;
        bfr[ni] = *(const bf16x8*)(Bsg + row * 64 + (((sub * 4 + quad) ^ (row & 7)) * 8));
      }
#pragma unroll
      for (int mi = 0; mi < 4; mi++)
#pragma unroll
        for (int ni = 0; ni < 2; ni++)
          acc[mi][ni] = __builtin_amdgcn_mfma_f32_16x16x32_bf16(af[mi], bfr[ni], acc[mi][ni], 0, 0, 0);
    }
  }

  // combine: group 1 -> LDS (reuse As, 32KB), group 0 adds + stores
  __syncthreads();
  float* comb = (float*)&As[0][0];
  if (grp == 1) {
#pragma unroll
    for (int mi = 0; mi < 4; mi++)
#pragma unroll
      for (int ni = 0; ni < 2; ni++)
        *(f32x4*)(comb + ((w4 * 8 + mi * 2 + ni) * 256 + lane * 4)) = acc[mi][ni];
  }
  __syncthreads();
  if (grp == 0) {
#pragma unroll
    for (int mi = 0; mi < 4; mi++) {
#pragma unroll
      for (int ni = 0; ni < 2; ni++) {
        f32x4 oth = *(const f32x4*)(comb + ((w4 * 8 + mi * 2 + ni) * 256 + lane * 4));
        f32x4 v = acc[mi][ni] + oth;
#pragma unroll
        for (int r = 0; r < 4; r++) {
          const int m = m0 + wm + mi * 16 + quad * 4 + r;
          fo[(size_t)m * 1024 + n0 + wn + ni * 16 + l16] = v[r];
        }
      }
    }
  }
}

// ---------------- flash attention: block staging + split-K + S^T softmax ------
// (r10 config: XCD-local bh = bid&31, longest chunks first — unchanged)
__global__ __launch_bounds__(256) void attn_kernel(
    const unsigned short* __restrict__ qb, const unsigned short* __restrict__ kb,
    const unsigned short* __restrict__ vb, unsigned short* __restrict__ yb,
    unsigned short* __restrict__ po, float* __restrict__ pl) {
  const int tid = threadIdx.x;
  const int wave = tid >> 6, lane = tid & 63;
  const int quad = lane >> 4, l16 = lane & 15;

  const int bid = blockIdx.x;
  const int bh = bid & 31;          // XCD-local: all 63 blocks of bh on one XCD
  const int u = 62 - (bid >> 5);    // longest chunks first
  int qs, c, nch;
  if (u < 11) { qs = u; c = 0; nch = 1; }
  else if (u < 33) { int v = u - 11; qs = 11 + (v >> 1); c = v & 1; nch = 2; }
  else { int v = u - 33; qs = 22 + v / 3; c = v % 3; nch = 3; }
  const int nt = qs + 1;
  const int j0 = c * nt / nch, j1 = (c + 1) * nt / nch;
  const int b = bh >> 4, h = bh & 15;

  __shared__ unsigned short Ks[64 * 64];     // [s][d], chunk-swizzled
  __shared__ unsigned short Vt[64 * 64];     // [d][s], chunk-swizzled
  __shared__ unsigned short Ps[4 * 16 * 68]; // per-wave P [q][s], stride 68
  unsigned short* Pw = Ps + wave * 16 * 68;

  const unsigned short* Qg = qb + (size_t)bh * T_ * D_;
  const unsigned short* Kg = kb + (size_t)bh * T_ * D_;
  const unsigned short* Vg = vb + (size_t)bh * D_ * T_;

  // Q fragment (B-operand: n=q=l16, k=d=quad*8+j)
  const unsigned short* qp = Qg + (size_t)(qs * 64 + wave * 16 + l16) * D_ + quad * 8;
  bf16x8 qf0 = *(const bf16x8*)qp, qf1 = *(const bf16x8*)(qp + 32);

  f32x4 o[4] = {};
  float lacc = 0.f;
  const int qglob = qs * 64 + wave * 16 + l16;   // this lane's q (S^T: col=l16)
  const int sloc_base = quad * 4;                // s-local row base (S^T: row=quad*4+r)

  const int trow = tid >> 3, tch = tid & 7;

  for (int jt = j0; jt < j1; jt++) {
    const int s0 = jt * 64;
    __syncthreads();
    {
      const int r0 = trow, r1 = trow + 32;
      gld16(Kg + (size_t)(s0 + r0) * D_ + ((tch ^ (r0 & 7)) * 8), Ks + r0 * 64 + tch * 8);
      gld16(Kg + (size_t)(s0 + r1) * D_ + ((tch ^ (r1 & 7)) * 8), Ks + r1 * 64 + tch * 8);
      gld16(Vg + (size_t)r0 * T_ + s0 + ((tch ^ (r0 & 7)) * 8), Vt + r0 * 64 + tch * 8);
      gld16(Vg + (size_t)r1 * T_ + s0 + ((tch ^ (r1 & 7)) * 8), Vt + r1 * 64 + tch * 8);
    }
    __syncthreads();

    // S^T = K Q^T : K as A-operand, Q as B-operand.
    // C-layout of s[mi]: row = s-local = mi*16+quad*4+r, col = q = l16.
    f32x4 s[4];
#pragma unroll
    for (int mi = 0; mi < 4; mi++) {
      const int row = mi * 16 + l16, sw = row & 7;
      bf16x8 kf0 = *(const bf16x8*)(Ks + row * 64 + ((quad ^ sw) * 8));
      bf16x8 kf1 = *(const bf16x8*)(Ks + row * 64 + (((quad + 4) ^ sw) * 8));
      f32x4 z = {0.f, 0.f, 0.f, 0.f};
      z = __builtin_amdgcn_mfma_f32_16x16x32_bf16(kf0, qf0, z, 0, 0, 0);
      s[mi] = __builtin_amdgcn_mfma_f32_16x16x32_bf16(kf1, qf1, z, 0, 0, 0);
    }

    if (jt == qs) {  // uniform diag branch: mask s > q
#pragma unroll
      for (int mi = 0; mi < 4; mi++)
#pragma unroll
        for (int r = 0; r < 4; r++) {
          float p = EXP2(s[mi][r]);
          p = (s0 + mi * 16 + sloc_base + r > qglob) ? 0.f : p;
          s[mi][r] = p;
          lacc += p;
        }
    } else {
#pragma unroll
      for (int mi = 0; mi < 4; mi++)
#pragma unroll
        for (int r = 0; r < 4; r++) {
          float p = EXP2(s[mi][r]);
          s[mi][r] = p;
          lacc += p;
        }
    }

    // P -> LDS [q=l16][s], packed dwords
#pragma unroll
    for (int mi = 0; mi < 4; mi++) {
      unsigned d0 = pack_bf2(s[mi][0], s[mi][1]);
      unsigned d1 = pack_bf2(s[mi][2], s[mi][3]);
      *(uint2*)(Pw + l16 * 68 + mi * 16 + quad * 4) = make_uint2(d0, d1);
    }

    // O += P V : P as A-operand (m=q=l16, k=s), V^T as B-operand
#pragma unroll
    for (int kk = 0; kk < 2; kk++) {
      bf16x8 pf = *(const bf16x8*)(Pw + l16 * 68 + kk * 32 + quad * 8);
#pragma unroll
      for (int ni = 0; ni < 4; ni++) {
        const int row = ni * 16 + l16, sw = row & 7;
        bf16x8 vf = *(const bf16x8*)(Vt + row * 64 + (((kk * 4 + quad) ^ sw) * 8));
        o[ni] = __builtin_amdgcn_mfma_f32_16x16x32_bf16(pf, vf, o[ni], 0, 0, 0);
      }
    }
  }

  // l: sum across the 4 lanes sharing l16 (quads), then fetch per-row values
  lacc += __shfl_xor(lacc, 16, 64);
  lacc += __shfl_xor(lacc, 32, 64);
  float lr[4];
#pragma unroll
  for (int r = 0; r < 4; r++) lr[r] = __shfl(lacc, quad * 4 + r, 16);  // l for q-row quad*4+r

  if (nch == 1) {
#pragma unroll
    for (int r = 0; r < 4; r++) {
      float inv = 1.0f / lr[r];
      int tq = qs * 64 + wave * 16 + quad * 4 + r;
#pragma unroll
      for (int ni = 0; ni < 4; ni++)
        yb[((size_t)(b * T_ + tq)) * 1024 + h * 64 + ni * 16 + l16] = f2bf(o[ni][r] * inv);
    }
  } else {
    const int slot = 52 * bh + ((qs <= 21) ? ((qs - 11) * 2 + c) : (22 + (qs - 22) * 3 + c));
    unsigned short* pob = po + (size_t)slot * 4096;
#pragma unroll
    for (int r = 0; r < 4; r++) {
      const int row64 = wave * 16 + quad * 4 + r;
#pragma unroll
      for (int ni = 0; ni < 4; ni++)
        pob[row64 * 64 + ni * 16 + l16] = f2bf(o[ni][r]);
      if (l16 == 0) pl[slot * 64 + row64] = lr[r];
    }
  }
}

// ---------------- split-K reduce: rows of strips qs>=11 ----------------
__global__ __launch_bounds__(256) void reduce_kernel(
    const unsigned short* __restrict__ po, const float* __restrict__ pl,
    unsigned short* __restrict__ yb) {
  int idx = blockIdx.x * 256 + threadIdx.x;
  int bh = idx / 21504;          // 1344 rows * 16 colgroups
  int rem = idx - bh * 21504;
  int rr = rem >> 4, cg = rem & 15;
  int qs = 11 + (rr >> 6), row64 = rr & 63;
  int base, nch;
  if (qs <= 21) { base = (qs - 11) * 2; nch = 2; }
  else { base = 22 + (qs - 22) * 3; nch = 3; }
  int b = bh >> 4, h = bh & 15;
  float a0 = 0.f, a1 = 0.f, a2 = 0.f, a3 = 0.f, l = 0.f;
  for (int cc = 0; cc < nch; cc++) {
    int slot = 52 * bh + base + cc;
    const unsigned short* p = po + (size_t)slot * 4096 + row64 * 64 + cg * 4;
    ushort4 uv = *(const ushort4*)p;
    a0 += bf2f(uv.x); a1 += bf2f(uv.y); a2 += bf2f(uv.z); a3 += bf2f(uv.w);
    l += pl[slot * 64 + row64];
  }
  float inv = 1.0f / l;
  int tq = qs * 64 + row64;
  ushort4 w;
  w.x = f2bf(a0 * inv); w.y = f2bf(a1 * inv); w.z = f2bf(a2 * inv); w.w = f2bf(a3 * inv);
  *(ushort4*)(yb + ((size_t)(b * T_ + tq)) * 1024 + h * 64 + cg * 4) = w;
}

// ---------------- launch ----------------
extern "C" void kernel_launch(void* const* d_in, const int* in_sizes, int n_in,
                              void* d_out, int out_size, void* d_ws, size_t ws_size,
                              hipStream_t stream) {
  const float* x = (const float*)d_in[0];       // [B,T,C]
  const float* w_qkv = (const float*)d_in[1];   // [C,3C]
  const float* w_proj = (const float*)d_in[2];  // [C,C]
  float* out = (float*)d_out;                   // [B,T,C] fp32

  // ws layout (shorts). po aliases wqkvT (dead after GEMM1). ~49.7 MB total.
  unsigned short* xb = (unsigned short*)d_ws;                 // 4.19M
  unsigned short* wprojT = xb + (size_t)BT_ * C_;             // 1.05M
  unsigned short* qb = wprojT + (size_t)C_ * C_;              // 4.19M
  unsigned short* kb = qb + (size_t)B_ * H_ * T_ * D_;        // 4.19M
  unsigned short* vb = kb + (size_t)B_ * H_ * T_ * D_;        // 4.19M
  unsigned short* wqkvT = vb + (size_t)B_ * H_ * T_ * D_;     // 3.15M
  unsigned short* po = wqkvT;                                 // 1664 slots * 4096 = 6.82M
  float* pl = (float*)(po + (size_t)1664 * 4096);             // 106K fp32
  unsigned short* yb = xb;  // reuse (x dead after GEMM1)

  prep_kernel<<<dim3(8192), 256, 0, stream>>>(x, xb, w_qkv, wqkvT, w_proj, wprojT);

  gemm_kernel<0><<<dim3(N3_ / 64, BT_ / 128), 256, 0, stream>>>(xb, wqkvT, qb, kb, vb, nullptr);
  attn_kernel<<<dim3(32 * 63), 256, 0, stream>>>(qb, kb, vb, yb, po, pl);
  reduce_kernel<<<dim3(2688), 256, 0, stream>>>(po, pl, yb);
  gemm2_kernel<<<dim3(C_ / 64, BT_ / 128), 512, 0, stream>>>(yb, wprojT, out);
}